// Round 1
// baseline (414.516 us; speedup 1.0000x reference)
//
#include <hip/hip_runtime.h>
#include <math.h>

// Problem constants: B=128,N=8 -> M=1024 rows; D=768; T=512; V=49408
#define VDIM    49408
#define NCH     193          // 49408 / 256 v-chunks
#define NSPLIT  16           // V splits; s = blockIdx&15 -> all 16 WGs of split on XCD s%8
#define NQT     16           // 1024 / 64 query tiles

typedef __bf16 bf16;
typedef __bf16 bf16x8 __attribute__((ext_vector_type(8)));
typedef float  f32x4  __attribute__((ext_vector_type(4)));

// ---------------- Kernel A: kw = audio@W + b, row-normalize -> kwn (bf16) ----
__global__ __launch_bounds__(256) void k_proj(const float* __restrict__ audio,
        const float* __restrict__ W, const float* __restrict__ bias,
        bf16* __restrict__ kwn) {
    __shared__ float a_lds[4 * 768];
    __shared__ float kw_lds[4 * 512];
    __shared__ float rn_lds[4];
    const int tid = threadIdx.x;
    const int q0 = blockIdx.x * 4;

    const float4* asrc = (const float4*)(audio + q0 * 768);
    float4* adst = (float4*)a_lds;
    #pragma unroll
    for (int i = 0; i < 3; ++i) adst[i * 256 + tid] = asrc[i * 256 + tid];
    __syncthreads();

    float acc0[4] = {0.f, 0.f, 0.f, 0.f}, acc1[4] = {0.f, 0.f, 0.f, 0.f};
    #pragma unroll 4
    for (int d = 0; d < 768; ++d) {
        const float w0 = W[d * 512 + tid];
        const float w1 = W[d * 512 + 256 + tid];
        #pragma unroll
        for (int q = 0; q < 4; ++q) {
            const float a = a_lds[q * 768 + d];   // broadcast, conflict-free
            acc0[q] = fmaf(a, w0, acc0[q]);
            acc1[q] = fmaf(a, w1, acc1[q]);
        }
    }
    const float b0 = bias[tid], b1 = bias[256 + tid];
    #pragma unroll
    for (int q = 0; q < 4; ++q) {
        kw_lds[q * 512 + tid]       = acc0[q] + b0;
        kw_lds[q * 512 + 256 + tid] = acc1[q] + b1;
    }
    __syncthreads();

    const int w = tid >> 6, lane = tid & 63;
    {   // wave w handles row w
        float ss = 0.f;
        #pragma unroll
        for (int i = 0; i < 8; ++i) { const float x = kw_lds[w * 512 + lane + i * 64]; ss = fmaf(x, x, ss); }
        #pragma unroll
        for (int o = 1; o < 64; o <<= 1) ss += __shfl_xor(ss, o);
        if (lane == 0) rn_lds[w] = 1.0f / fmaxf(sqrtf(ss), 1e-8f);
    }
    __syncthreads();
    #pragma unroll
    for (int i = 0; i < 8; ++i) {
        const int idx = i * 256 + tid;
        const int q = idx >> 9;
        kwn[(q0 + q) * 512 + (idx & 511)] = (bf16)(kw_lds[idx] * rn_lds[q]);
    }
}

// ---------------- Kernel B: one-pass emb prep --------------------------------
__global__ __launch_bounds__(256) void k_prep(const float* __restrict__ emb,
        bf16* __restrict__ embS, bf16* __restrict__ embT, float* __restrict__ rs) {
    __shared__ unsigned short tile[64 * 512];
    __shared__ float pnorm[64 * 2];
    const int tid = threadIdx.x;
    const int b = blockIdx.x;
    const int v0 = b * 64;
    const int lane = tid & 63;
    const int p = (tid >> 6) & 1;          // wave parity within row

    // 1: coalesced load + fp32 norm partials + bf16 convert + swizzled LDS store
    const float4* src = (const float4*)(emb + (size_t)v0 * 512);
    #pragma unroll
    for (int i = 0; i < 32; ++i) {
        const int L = i * 256 + tid;           // float4 index in 64x128
        const int r = L >> 7, c4 = L & 127;    // whole wave shares one row r
        const float4 x = src[L];
        float ss = x.x * x.x + x.y * x.y + x.z * x.z + x.w * x.w;
        #pragma unroll
        for (int o = 1; o < 64; o <<= 1) ss += __shfl_xor(ss, o);
        if (lane == 0) pnorm[r * 2 + p] = ss;
        const int g = c4 >> 1, half = c4 & 1;
        ushort4 u;
        u.x = __builtin_bit_cast(unsigned short, (bf16)x.x);
        u.y = __builtin_bit_cast(unsigned short, (bf16)x.y);
        u.z = __builtin_bit_cast(unsigned short, (bf16)x.z);
        u.w = __builtin_bit_cast(unsigned short, (bf16)x.w);
        *(ushort4*)&tile[r * 512 + (((g ^ (r & 7)) << 3) + half * 4)] = u;
    }
    __syncthreads();
    if (tid < 64) {
        const float ss = pnorm[tid * 2] + pnorm[tid * 2 + 1];
        // folds 1/TEMP (=10) AND log2(e): producer uses exp2f
        rs[v0 + tid] = 14.426950408889634f / fmaxf(sqrtf(ss), 1e-8f);
    }

    // 2: embS frag-major (uint4 LDS reads, fully coalesced global writes)
    #pragma unroll
    for (int i = 0; i < 16; ++i) {
        const int F = i * 256 + tid;           // out granule 0..4095
        const int frag = F >> 6, l = F & 63;
        const int vt = frag >> 4, kf = frag & 15;
        const int lm = l & 15, lg = l >> 4;
        const int r = vt * 16 + lm, g = kf * 4 + lg;
        const uint4 d = *(const uint4*)&tile[r * 512 + ((g ^ (r & 7)) << 3)];
        *(uint4*)((unsigned short*)embS + ((size_t)(b * 4 + vt) * 16 + kf) * 512 + l * 8) = d;
    }
    // 3: embT frag-major (transpose gather from LDS, coalesced writes)
    #pragma unroll
    for (int i = 0; i < 16; ++i) {
        const int F = i * 256 + tid;
        const int frag = F >> 6, l = F & 63;
        const int kvl = frag >> 5, tt = frag & 31;
        const int lm = l & 15, lg = l >> 4;
        const int t = tt * 16 + lm;
        unsigned short e[8];
        #pragma unroll
        for (int j = 0; j < 8; ++j) {
            const int r = kvl * 32 + lg * 8 + j;
            e[j] = tile[r * 512 + ((((t >> 3) ^ (r & 7)) << 3) + (t & 7))];
        }
        uint4 o;
        o.x = (unsigned)e[0] | ((unsigned)e[1] << 16);
        o.y = (unsigned)e[2] | ((unsigned)e[3] << 16);
        o.z = (unsigned)e[4] | ((unsigned)e[5] << 16);
        o.w = (unsigned)e[6] | ((unsigned)e[7] << 16);
        const int kvg = b * 2 + kvl;           // global v/32 index
        *(uint4*)((unsigned short*)embT + ((size_t)kvg * 32 + tt) * 512 + l * 8) = o;
    }
}

// ---------------- Kernel C: M64 producer/consumer fused attention ------------
// 768 threads = 12 waves. Waves 0-3 (producers): S^T = En@Qn^T (swapped
// operands so each lane holds 4 CONSECUTIVE v per reg group -> exp2 + packed
// conflict-free ds_write_b64 into the consumer frag layout). Waves 4-11
// (consumers): O += P@E, each a 64-wide t-slice, 3-buffer distance-2 E
// prefetch. Fine-grained per-producer flags both directions: consumer waits
// producer p only before kf-pair {2p,2p+1} and releases p's region right
// after; producer p waits only on its own region.
__global__ __launch_bounds__(768, 3) void k_attn(const bf16* __restrict__ kwn,
        const bf16* __restrict__ embS, const bf16* __restrict__ embT,
        const float* __restrict__ rs, float* __restrict__ Oacc,
        float* __restrict__ Lsum) {
    __shared__ __align__(16) unsigned short Qlds[64 * 512];   // 64 KB, XOR-swizzled granules
    __shared__ __align__(16) unsigned short Plds[2 * 16384];  // 64 KB: 2 slots x (64q x 256v)
    __shared__ int prod_done[2][4], cons_done[2][4];
    const int tid = threadIdx.x;
    const int s = blockIdx.x & (NSPLIT - 1), qt = blockIdx.x >> 4;
    const int q0 = qt * 64;
    const int wg = tid >> 6, lane = tid & 63, lm = lane & 15, lg = lane >> 4;

    if (tid < 8) { prod_done[tid >> 2][tid & 3] = 0; cons_done[tid >> 2][tid & 3] = 0; }
    if (tid < 512) {   // stage Q tile (64x512 bf16), granule-swizzled g' = g^(q&7)
        const uint4* src = (const uint4*)(kwn + q0 * 512);
        #pragma unroll
        for (int i = 0; i < 8; ++i) {
            const int L = (i * 512 + tid) * 8;
            const int q = L >> 9, g = (L & 511) >> 3;
            *(uint4*)&Qlds[q * 512 + ((g ^ (q & 7)) << 3)] = src[i * 512 + tid];
        }
    }
    __syncthreads();   // covers Q staging + flag init

    const f32x4 zero4 = {0.f, 0.f, 0.f, 0.f};
    const int c0 = (s * NCH) / NSPLIT, c1 = ((s + 1) * NCH) / NSPLIT;
    const int n = c1 - c0;

    if (wg < 4) {
        // ================= producer: v-slice wg*64, all 64 q =================
        // swapped-operand S^T: lane holds S[q = mb*16+lm][v = wg*64+nb*16+lg*4+r]
        float lacc[4] = {0.f, 0.f, 0.f, 0.f};   // per-lane P row-sum partial, q = mb*16+lm
        for (int i = 0; i < n; ++i) {
            const int c = c0 + i;
            const int slot = i & 1, use = i >> 1;
            // rs preload (flag-independent; latency hides under S-compute)
            float4 rs4[4];
            #pragma unroll
            for (int nb = 0; nb < 4; ++nb)
                rs4[nb] = ((const float4*)(rs + c * 256 + wg * 64 + nb * 16))[lg];
            // ---- S^T compute (flag-independent), kf-pipelined E dbuf ----
            f32x4 sacc[4][4];
            #pragma unroll
            for (int mb = 0; mb < 4; ++mb)
                #pragma unroll
                for (int nb = 0; nb < 4; ++nb) sacc[mb][nb] = zero4;
            const bf16* Eb = embS + ((size_t)(c * 16 + wg * 4) * 16) * 512 + lane * 8;
            bf16x8 ebA[4], ebB[4];
            #pragma unroll
            for (int nb = 0; nb < 4; ++nb) ebA[nb] = *(const bf16x8*)(Eb + (nb * 16) * 512);
            #pragma unroll
            for (int kf = 0; kf < 16; ++kf) {
                const bf16x8* cur = (kf & 1) ? ebB : ebA;
                bf16x8* nxt = (kf & 1) ? ebA : ebB;
                if (kf < 15) {
                    #pragma unroll
                    for (int nb = 0; nb < 4; ++nb)
                        nxt[nb] = *(const bf16x8*)(Eb + (nb * 16 + kf + 1) * 512);
                }
                const int goff = ((kf * 4 + lg) ^ (lm & 7)) << 3;
                bf16x8 aq[4];
                #pragma unroll
                for (int mb = 0; mb < 4; ++mb)
                    aq[mb] = *(const bf16x8*)&Qlds[(mb * 16 + lm) * 512 + goff];
                __builtin_amdgcn_s_setprio(1);
                #pragma unroll
                for (int nb = 0; nb < 4; ++nb)
                    #pragma unroll
                    for (int mb = 0; mb < 4; ++mb)
                        sacc[mb][nb] = __builtin_amdgcn_mfma_f32_16x16x32_bf16(cur[nb], aq[mb], sacc[mb][nb], 0, 0, 0);
                __builtin_amdgcn_s_setprio(0);
                __builtin_amdgcn_sched_barrier(0);
            }
            // ---- wait OWN region free, then exp2 + contiguous packed writes ----
            while (__hip_atomic_load(&cons_done[slot][wg], __ATOMIC_ACQUIRE,
                                     __HIP_MEMORY_SCOPE_WORKGROUP) < 8 * use)
                __builtin_amdgcn_s_sleep(1);
            unsigned short* Pw = Plds + (slot << 14);
            #pragma unroll
            for (int nb = 0; nb < 4; ++nb) {
                const float4 rv = rs4[nb];
                const int kfc = wg * 2 + (nb >> 1);
                const int off = (lm + 16 * ((nb & 1) * 2 + (lg >> 1))) * 8 + (lg & 1) * 4;
                #pragma unroll
                for (int mb = 0; mb < 4; ++mb) {
                    const bf16 b0 = (bf16)exp2f(sacc[mb][nb][0] * rv.x);
                    const bf16 b1 = (bf16)exp2f(sacc[mb][nb][1] * rv.y);
                    const bf16 b2 = (bf16)exp2f(sacc[mb][nb][2] * rv.z);
                    const bf16 b3 = (bf16)exp2f(sacc[mb][nb][3] * rv.w);
                    lacc[mb] += ((float)b0 + (float)b1) + ((float)b2 + (float)b3);
                    ushort4 w4;
                    w4.x = __builtin_bit_cast(unsigned short, b0);
                    w4.y = __builtin_bit_cast(unsigned short, b1);
                    w4.z = __builtin_bit_cast(unsigned short, b2);
                    w4.w = __builtin_bit_cast(unsigned short, b3);
                    *(ushort4*)&Pw[(mb * 8 + kfc) * 512 + off] = w4;   // conflict-free b64
                }
            }
            if (lane == 0)   // release drains LDS writes
                __hip_atomic_fetch_add(&prod_done[slot][wg], 1, __ATOMIC_RELEASE,
                                       __HIP_MEMORY_SCOPE_WORKGROUP);
        }
        // Lsum: lanes sharing lm hold partials for q = mb*16+lm; reduce over lg
        #pragma unroll
        for (int mb = 0; mb < 4; ++mb) {
            float sum = lacc[mb];
            sum += __shfl_xor(sum, 16);
            sum += __shfl_xor(sum, 32);
            if (lane < 16) atomicAdd(&Lsum[q0 + mb * 16 + lm], sum);
        }
    } else {
        // ================= consumer: t-slice (wg-4)*64, all 64 q =============
        const int cw = wg - 4;
        f32x4 acc[4][4];                   // [mb 16q][nt 16t]
        #pragma unroll
        for (int mb = 0; mb < 4; ++mb)
            #pragma unroll
            for (int nt = 0; nt < 4; ++nt) acc[mb][nt] = zero4;
        for (int i = 0; i < n; ++i) {
            const int cc = c0 + i;
            const int slot = i & 1, use = i >> 1;
            const bf16* ETb = embT + ((size_t)cc * 256 + cw * 4) * 512 + lane * 8;
            // 3-buffer distance-2 E prefetch; kf=0,1 issued BEFORE any flag wait
            bf16x8 et[3][4];
            #pragma unroll
            for (int nt = 0; nt < 4; ++nt) {
                et[0][nt] = *(const bf16x8*)(ETb + nt * 512);
                et[1][nt] = *(const bf16x8*)(ETb + (32 + nt) * 512);
            }
            const unsigned short* Pb = Plds + (slot << 14);
            #pragma unroll
            for (int p = 0; p < 4; ++p) {
                while (__hip_atomic_load(&prod_done[slot][p], __ATOMIC_ACQUIRE,
                                         __HIP_MEMORY_SCOPE_WORKGROUP) < use + 1)
                    __builtin_amdgcn_s_sleep(1);
                #pragma unroll
                for (int kh = 0; kh < 2; ++kh) {
                    const int kf = 2 * p + kh;
                    if (kf < 6) {          // distance-2 prefetch, static %3 rotation
                        #pragma unroll
                        for (int nt = 0; nt < 4; ++nt)
                            et[(kf + 2) % 3][nt] = *(const bf16x8*)(ETb + ((kf + 2) * 32 + nt) * 512);
                    }
                    bf16x8 pf[4];
                    #pragma unroll
                    for (int mb = 0; mb < 4; ++mb)
                        pf[mb] = *(const bf16x8*)&Pb[(mb * 8 + kf) * 512 + lane * 8];
                    __builtin_amdgcn_s_setprio(1);
                    #pragma unroll
                    for (int nt = 0; nt < 4; ++nt)
                        #pragma unroll
                        for (int mb = 0; mb < 4; ++mb)
                            acc[mb][nt] = __builtin_amdgcn_mfma_f32_16x16x32_bf16(pf[mb], et[kf % 3][nt], acc[mb][nt], 0, 0, 0);
                    __builtin_amdgcn_s_setprio(0);
                }
                if (lane == 0)   // release producer p's region (drains LDS reads)
                    __hip_atomic_fetch_add(&cons_done[slot][p], 1, __ATOMIC_RELEASE,
                                           __HIP_MEMORY_SCOPE_WORKGROUP);
            }
        }
        // epilogue: combine partials across v-splits
        #pragma unroll
        for (int mb = 0; mb < 4; ++mb)
            #pragma unroll
            for (int nt = 0; nt < 4; ++nt)
                #pragma unroll
                for (int r = 0; r < 4; ++r) {
                    const int q = q0 + mb * 16 + lg * 4 + r;
                    const int t = cw * 64 + nt * 16 + lm;
                    atomicAdd(&Oacc[q * 512 + t], acc[mb][nt][r]);
                }
    }
}

// ---------------- Kernel D: out = Oacc / Lsum --------------------------------
__global__ __launch_bounds__(256) void k_final(const float* __restrict__ Oacc,
        const float* __restrict__ Lsum, float* __restrict__ out) {
    const int i = blockIdx.x * 256 + threadIdx.x;   // float4 index, 131072 total
    const float4 o = ((const float4*)Oacc)[i];
    const float inv = 1.0f / Lsum[i >> 7];          // 128 float4 per row
    float4 r;
    r.x = o.x * inv; r.y = o.y * inv; r.z = o.z * inv; r.w = o.w * inv;
    ((float4*)out)[i] = r;
}

// ---------------- launcher ---------------------------------------------------
// ws layout (bytes) — total 104,535,040 (proven to fit):
//   0        kwn   bf16 [1024*512]          1,048,576
//   1048576  rs    f32  [49408]               197,632
//   1246208  Oacc  f32  [1024*512]          2,097,152   (zeroed each launch)
//   3343360  Lsum  f32  [1024]                   4,096   (zeroed each launch)
//   3347456  embS  bf16 frag-major          50,593,792
//   53941248 embT  bf16 frag-major          50,593,792
extern "C" void kernel_launch(void* const* d_in, const int* in_sizes, int n_in,
                              void* d_out, int out_size, void* d_ws, size_t ws_size,
                              hipStream_t stream) {
    const float* audio = (const float*)d_in[0];
    const float* W     = (const float*)d_in[1];
    const float* bias  = (const float*)d_in[2];
    const float* emb   = (const float*)d_in[3];
    float* out = (float*)d_out;
    char* ws = (char*)d_ws;

    bf16*  kwn  = (bf16*)(ws);
    float* rs   = (float*)(ws + 1048576);
    float* Oacc = (float*)(ws + 1246208);
    float* Lsum = (float*)(ws + 3343360);
    bf16*  embS = (bf16*)(ws + 3347456);
    bf16*  embT = (bf16*)(ws + 53941248);

    hipMemsetAsync(ws + 1246208, 0, 2097152 + 4096, stream);   // Oacc + Lsum
    k_proj<<<256, 256, 0, stream>>>(audio, W, bias, kwn);
    k_prep<<<VDIM / 64, 256, 0, stream>>>(emb, embS, embT, rs);
    k_attn<<<NQT * NSPLIT, 768, 0, stream>>>(kwn, embS, embT, rs, Oacc, Lsum);
    k_final<<<(out_size / 4) / 256, 256, 0, stream>>>(Oacc, Lsum, out);
}